// Round 1
// baseline (70.448 us; speedup 1.0000x reference)
//
#include <hip/hip_runtime.h>

#define NM   20          // nmax
#define NP1  21
#define NPAIR 441        // (nmax+1)^2 (n,m) channel pairs
#define PTS  16          // points per block
#define BLK  256

struct Tbl {
    float dprod[NP1];          // INV_SQRT_4PI * prod_{k<=m} (-sqrt((2k+1)/(2k)))
    float e[NP1];              // sqrt(2m+3)
    float a[NP1][NP1];         // recurrence a(m,n)
    float b[NP1][NP1];         // recurrence b(m,n)
    unsigned short cmap[NPAIR];// per channel-pair: pidx(9b) | am<<9 | negRe<<14 | negIm<<15
};

constexpr double csqrt_d(double x) {
    double r = x * 0.5 + 0.5;
    for (int i = 0; i < 48; ++i) r = 0.5 * (r + x / r);
    return r;
}

constexpr Tbl make_tbl() {
    Tbl t{};
    const double inv4pi = 0.28209479177387814;  // 1/sqrt(4*pi)
    double dp = inv4pi;
    t.dprod[0] = (float)dp;
    for (int m = 1; m <= NM; ++m) {
        dp *= -csqrt_d((2.0 * m + 1.0) / (2.0 * m));   // Condon-Shortley phase
        t.dprod[m] = (float)dp;
    }
    for (int m = 0; m <= NM; ++m) t.e[m] = (float)csqrt_d(2.0 * m + 3.0);
    for (int m = 0; m <= NM; ++m)
        for (int n = m + 2; n <= NM; ++n) {
            double nn = (double)n * n, mm = (double)m * m;
            t.a[m][n] = (float)csqrt_d((4.0 * nn - 1.0) / (nn - mm));
            t.b[m][n] = (float)csqrt_d((2.0 * n + 1.0) * (n - 1.0 - m) * (n - 1.0 + m) /
                                       ((2.0 * n - 3.0) * (nn - mm)));
        }
    int ch = 0;
    for (int n = 0; n <= NM; ++n)
        for (int mm = -n; mm <= n; ++mm) {
            int am = mm < 0 ? -mm : mm;
            unsigned pidx = (unsigned)(n * NP1 + am);
            unsigned negRe = (mm < 0 && (am & 1)) ? 1u : 0u;   // Y_n^{-m}: re *= (-1)^m
            unsigned negIm = (mm < 0 && !(am & 1)) ? 1u : 0u;  //            im *= -(-1)^m
            t.cmap[ch++] = (unsigned short)(pidx | (unsigned)(am << 9) | (negRe << 14) | (negIm << 15));
        }
    return t;
}

__constant__ Tbl TBL = make_tbl();

// LDS layout per point: [0..440] = Pbar(n*21+m), [441..461] = cos(m*theta), [462..482] = sin(m*theta)
__global__ __launch_bounds__(BLK) void sph_kernel(const float* __restrict__ theta,
                                                  const float* __restrict__ phi,
                                                  float* __restrict__ out, int npts) {
    __shared__ float sh[PTS][484];
    __shared__ unsigned short cm[NPAIR];
    const int tid = threadIdx.x;
    for (int i = tid; i < NPAIR; i += BLK) cm[i] = TBL.cmap[i];

    const int pt  = tid >> 4;     // point within block
    const int sub = tid & 15;     // worker within point
    const int gpt = blockIdx.x * PTS + pt;

    if (gpt < npts) {
        const float ph = phi[gpt];
        const float x = cosf(ph);                                // cos(polar)
        const float s = sqrtf(fmaxf(1.0f - x * x, 0.0f));
        // each worker owns m-columns {sub, sub+16}
        for (int m = sub; m <= NM; m += 16) {
            float pmm = TBL.dprod[m];
            for (int k = 0; k < m; ++k) pmm *= s;                // * s^m
            sh[pt][m * NP1 + m] = pmm;
            if (m < NM) {
                float pa = TBL.e[m] * x * pmm;                   // P_{m+1}^m
                sh[pt][(m + 1) * NP1 + m] = pa;
                float pb = pmm;
                for (int n = m + 2; n <= NM; ++n) {
                    float pn = TBL.a[m][n] * x * pa - TBL.b[m][n] * pb;
                    sh[pt][n * NP1 + m] = pn;
                    pb = pa; pa = pn;
                }
            }
        }
        if (sub == 0) {  // trig tables: cos/sin(m*theta) via Chebyshev
            const float th = theta[gpt];
            float st, ct;
            sincosf(th, &st, &ct);
            sh[pt][441] = 1.0f; sh[pt][462] = 0.0f;
            sh[pt][442] = ct;   sh[pt][463] = st;
            float c2 = 1.0f, c1 = ct, s2 = 0.0f, s1 = st;
            for (int k = 2; k <= NM; ++k) {
                float ck = 2.0f * ct * c1 - c2;
                float sk = 2.0f * ct * s1 - s2;
                sh[pt][441 + k] = ck; sh[pt][462 + k] = sk;
                c2 = c1; c1 = ck; s2 = s1; s1 = sk;
            }
        }
    }
    __syncthreads();

    // Phase 2: coalesced float2 (re,im) stores over the block's 16*441 channel pairs
    const int vpts = min(PTS, npts - (int)blockIdx.x * PTS);
    const int total = vpts * NPAIR;
    const long long base = (long long)blockIdx.x * PTS * (2 * NPAIR);
    for (int j = tid; j < total; j += BLK) {
        const int p = j / NPAIR;
        const int c = j - p * NPAIR;
        const unsigned e = cm[c];
        const int pidx = e & 511;
        const int am = (e >> 9) & 31;
        const float P = sh[p][pidx];
        float re = P * sh[p][441 + am];
        float im = P * sh[p][462 + am];
        if (e & (1u << 14)) re = -re;
        if (e & (1u << 15)) im = -im;
        float2 v = make_float2(re, im);
        *reinterpret_cast<float2*>(out + base + 2ll * j) = v;
    }
}

extern "C" void kernel_launch(void* const* d_in, const int* in_sizes, int n_in,
                              void* d_out, int out_size, void* d_ws, size_t ws_size,
                              hipStream_t stream) {
    const float* theta = (const float*)d_in[0];
    const float* phi   = (const float*)d_in[1];
    float* out = (float*)d_out;
    const int npts = in_sizes[0];
    const int blocks = (npts + PTS - 1) / PTS;
    sph_kernel<<<blocks, BLK, 0, stream>>>(theta, phi, out, npts);
}